// Round 8
// baseline (328.066 us; speedup 1.0000x reference)
//
#include <hip/hip_runtime.h>
#include <hip/hip_cooperative_groups.h>

#define T_LEN 2048
#define NMODE 8
#define NPP   17   // 8 tau + 9 g (g[0]=g_infy)

namespace cg = cooperative_groups;

typedef float f32x4 __attribute__((ext_vector_type(4)));

static __device__ __forceinline__ void nt_store4(float* p, float a, float b,
                                                 float c, float d) {
    f32x4 v = {a, b, c, d};
    __builtin_nontemporal_store(v, (f32x4*)p);
}

// ===========================================================================
// Round 8: single cooperative kernel — ONE pass + grid.sync().
//
// R5-R7 post-mortem: every 2-kernel variant pins at ~26-28us kernel time
// because BOTH kernels repeat the coeff+scan pass (the split buys one
// grid-wide sync at the cost of ~2x recompute). grid.sync() buys the same
// sync for ~2-3us and keeps all per-tile LDS state (qT, ca, Zrel, Pp) alive
// across it, so the post-sync work is just lookback-fold + epilogue.
//
// Publish protocol: relaxed agent stores + per-wave vmcnt drain (proven
// cheap in R2 — no L2 cache-maintenance storm), then grid.sync().
// Fallback: if cooperative launch is rejected, run the proven R6 2-kernel
// path (aggK + finK below).
// ===========================================================================
template <int L, int G>
__global__ __launch_bounds__(256, 8)
void fusedCoop(const float* __restrict__ Se,   // [B,T,3,3]
               const float* __restrict__ tt,   // [B,T]
               const float* __restrict__ pp,   // [B,T,17]
               float* __restrict__ out,        // [3,B,T,3,3]
               float* __restrict__ agg,        // [B*TILES][80] P[8]+R[72]
               int B) {
    constexpr int NSTEP = G * L;            // 128
    constexpr int TILES = T_LEN / NSTEP;    // 16
    constexpr int RW    = NSTEP + 1;        // 129
    constexpr int NT    = 256;
    constexpr int SROW  = NSTEP + 4;        // 132
    constexpr int QT_SZ = 9 * SROW;         // 1188
    constexpr int CA_K  = L * 8 + 4;        // 132
    constexpr int AC_K  = L * 16 + 4;       // 260
    constexpr int O_AC  = QT_SZ + G * CA_K; // 2244
    // overlay inside AC region (AC dead after scan phase):
    constexpr int OV_ZREL = 0;                   // G*72 = 576
    constexpr int OV_PP   = G * 72;              // G*8  = 64
    constexpr int OV_Z    = OV_PP + G * 8;       // G*72 = 576
    constexpr int OV_R    = OV_Z + G * 72;       // G*72 = 576
    constexpr int OV_P    = OV_R + G * 72;       // G*8  = 64
    static_assert(OV_P + G * 8 <= G * AC_K, "overlay fits in AC region");
    constexpr int O_INV = O_AC + G * AC_K;       // 4324
    constexpr int O_GI  = O_INV + RW;            // 4453
    constexpr int TOTAL = O_GI + RW;             // 4582 floats = 18328 B
    static_assert(TOTAL * 4 <= 20480, "LDS must allow 8 blocks/CU");
    static_assert(L == 16, "epilogue uses t>>4 / t&15");

    __shared__ __align__(16) float sm[TOTAL];
    float* s_qT   = sm;                      // qsum transposed [e][t]
    float* s_ca   = sm + QT_SZ;              // cumA skewed [k][s][8]
    float* s_AC   = sm + O_AC;               // coeffs (dead after scan)
    float* s_Zrel = sm + O_AC + OV_ZREL;
    float* s_Pp   = sm + O_AC + OV_PP;
    float* s_Z    = sm + O_AC + OV_Z;
    float* s_R    = sm + O_AC + OV_R;
    float* s_P    = sm + O_AC + OV_P;
    float* s_inv  = sm + O_INV;
    float* s_gi   = sm + O_GI;

    const int tid  = threadIdx.x;
    const int b    = blockIdx.x / TILES;
    const int tile = blockIdx.x % TILES;

    const int base = tile * NSTEP;
    const int off  = (base == 0) ? 0 : 1;
    const int r0   = (base == 0) ? 0 : base - 1;

    const float* ppb = pp + ((size_t)b * T_LEN + r0) * NPP;
    const float* ttb = tt + (size_t)b * T_LEN + r0;

    // ---- per-row 1/sum(g), g_infy/sum ----
    for (int i = tid; i < RW; i += NT) {
        const float* gp = ppb + i * NPP + 8;
        float gs = 0.f;
        #pragma unroll
        for (int k = 0; k < 9; ++k) gs += gp[k];
        float iv = __builtin_amdgcn_rcpf(gs);
        s_inv[i] = iv;
        s_gi[i]  = gp[0] * iv;
    }
    __syncthreads();

    // ---- per-(step,mode) coefficients ----
    for (int i = tid; i < NSTEP * 8; i += NT) {
        int m  = i & 7;
        int ts = i >> 3;
        int rc = ts + off;
        bool first = (base == 0) && (ts == 0);
        int rp = first ? rc : rc - 1;
        float tau_c = ppb[rc * NPP + m];
        float tau_p = ppb[rp * NPP + m];
        float gqh_c = 0.5f * ppb[rc * NPP + 9 + m] * s_inv[rc];
        float gqh_p = 0.5f * ppb[rp * NPP + 9 + m] * s_inv[rp];
        float t_c = ttb[rc];
        float t_p = first ? -ttb[1] : ttb[rp];
        float ee  = __expf((t_p - t_c) * __builtin_amdgcn_rcpf(tau_c + tau_p));
        int kk = ts / L, sl = ts % L;
        s_AC[kk * AC_K + sl * 16 + m]     = ee * ee;              // A
        s_AC[kk * AC_K + sl * 16 + 8 + m] = ee * (gqh_c + gqh_p); // C
    }
    __syncthreads();

    const size_t nOut = (size_t)B * T_LEN * 9;
    float* o0 = out + ((size_t)b * T_LEN + base) * 9;
    float* o1 = o0 + nOut;
    float* o2 = o0 + 2 * nOut;
    const float4* sv4 = (const float4*)(Se + ((size_t)b * T_LEN + base) * 9);

    // ---- scan: chunk scans (tid<72) | S_infy (72..191) | cumA (192..255) --
    float Q[8] = {0,0,0,0,0,0,0,0};
    float cumA_c = 1.f;
    if (tid < 72) {
        const int k = tid / 9;
        const int e = tid - k * 9;
        const float* Sg = Se + (size_t)b * T_LEN * 9 + e;
        const int gbase = base + k * L;

        float dS[L];
        {
            float prev = (base == 0 && k == 0) ? 0.f
                                               : Sg[(size_t)(gbase - 1) * 9];
            #pragma unroll
            for (int s = 0; s < L; ++s) {
                float cur = Sg[(size_t)(gbase + s) * 9];
                dS[s] = cur - prev;
                prev = cur;
            }
        }

        const float4* acp = (const float4*)(s_AC + k * AC_K);
        #pragma unroll
        for (int s = 0; s < L; ++s) {
            float4 a0 = acp[4*s], a1 = acp[4*s+1];
            float4 c0v = acp[4*s+2], c1v = acp[4*s+3];
            float d = dS[s];
            Q[0] = a0.x*Q[0] + c0v.x*d;  Q[1] = a0.y*Q[1] + c0v.y*d;
            Q[2] = a0.z*Q[2] + c0v.z*d;  Q[3] = a0.w*Q[3] + c0v.w*d;
            Q[4] = a1.x*Q[4] + c1v.x*d;  Q[5] = a1.y*Q[5] + c1v.y*d;
            Q[6] = a1.z*Q[6] + c1v.z*d;  Q[7] = a1.w*Q[7] + c1v.w*d;
            float qs = ((Q[0]+Q[1])+(Q[2]+Q[3])) + ((Q[4]+Q[5])+(Q[6]+Q[7]));
            s_qT[e * SROW + (k * L + s)] = qs;
        }
    } else if (tid < 192) {
        // S_infy plane — hidden behind the chunk scans
        for (int i4 = tid - 72; i4 < NSTEP * 9 / 4; i4 += 120) {
            float4 sv = sv4[i4];
            int i = i4 * 4;
            nt_store4(o1 + i,
                      s_gi[(i    ) / 9 + off] * sv.x,
                      s_gi[(i + 1) / 9 + off] * sv.y,
                      s_gi[(i + 2) / 9 + off] * sv.z,
                      s_gi[(i + 3) / 9 + off] * sv.w);
        }
    } else {
        const int u = tid - 192;
        const int k = u >> 3;
        const int m = u & 7;
        #pragma unroll
        for (int s = 0; s < L; ++s) {
            cumA_c *= s_AC[k * AC_K + s * 16 + m];
            s_ca[k * CA_K + s * 8 + m] = cumA_c;
        }
    }
    __syncthreads();   // last AC reads done -> overlay writable

    if (tid < 72) {
        float4* r4 = (float4*)(s_R + 8 * tid);   // k*72 + e*8 == 8*tid
        r4[0] = make_float4(Q[0], Q[1], Q[2], Q[3]);
        r4[1] = make_float4(Q[4], Q[5], Q[6], Q[7]);
    } else if (tid >= 192) {
        s_P[tid - 192] = cumA_c;
    }
    __syncthreads();

    // ---- compose across chunks; publish tile aggregate ----
    if (tid < 72) {
        const int e = tid >> 3;
        const int m = tid & 7;
        float z = 0.f, pprod = 1.f;
        #pragma unroll
        for (int k = 0; k < G; ++k) {
            s_Zrel[k * 72 + tid] = z;
            if (e == 0) s_Pp[k * 8 + m] = pprod;
            float Pk = s_P[k * 8 + m];
            z = Pk * z + s_R[k * 72 + tid];
            pprod *= Pk;
        }
        if (tile != TILES - 1) {   // last tile has no consumers
            float* ap = agg + ((size_t)b * TILES + tile) * 80;
            __hip_atomic_store(ap + 8 + tid, z, __ATOMIC_RELAXED,
                               __HIP_MEMORY_SCOPE_AGENT);
            if (e == 0)
                __hip_atomic_store(ap + m, pprod, __ATOMIC_RELAXED,
                                   __HIP_MEMORY_SCOPE_AGENT);
        }
    }
    // drain this wave's stores to the coherent point before the grid barrier
    asm volatile("s_waitcnt vmcnt(0)" ::: "memory");

    cg::this_grid().sync();

    // ---- lookback: batched relaxed loads, fold zin; fill s_Z ----
    if (tid < 72) {
        const int m = tid & 7;
        float zin = 0.f;
        if (tile > 0) {
            const float* ab = agg + (size_t)b * TILES * 80;
            float Pv[TILES - 1], Rv[TILES - 1];
            #pragma unroll
            for (int j = 0; j < TILES - 1; ++j) {
                if (j < tile) {
                    Pv[j] = __hip_atomic_load(ab + j * 80 + m,
                                              __ATOMIC_RELAXED,
                                              __HIP_MEMORY_SCOPE_AGENT);
                    Rv[j] = __hip_atomic_load(ab + j * 80 + 8 + tid,
                                              __ATOMIC_RELAXED,
                                              __HIP_MEMORY_SCOPE_AGENT);
                }
            }
            #pragma unroll
            for (int j = 0; j < TILES - 1; ++j)
                if (j < tile) zin = Pv[j] * zin + Rv[j];
        }
        #pragma unroll
        for (int k = 0; k < G; ++k)
            s_Z[k * 72 + tid] = s_Pp[k * 8 + m] * zin + s_Zrel[k * 72 + tid];
    }
    __syncthreads();

    // ---- epilogue: final S and Q_sum planes (LDS state still live) ----
    for (int i4 = tid; i4 < NSTEP * 9 / 4; i4 += NT) {
        float4 sv = sv4[i4];   // cache-warm re-read
        const float svc[4] = {sv.x, sv.y, sv.z, sv.w};
        int i = i4 * 4;
        float q[4], f[4];
        #pragma unroll
        for (int j = 0; j < 4; ++j) {
            int idx = i + j;
            int t = idx / 9, e = idx - t * 9;
            int rc = t + off;
            int k = t >> 4, s = t & 15;
            const float4* ca4 = (const float4*)(s_ca + k * CA_K + s * 8);
            const float4* z4  = (const float4*)(s_Z + k * 72 + e * 8);
            float4 cA = ca4[0], cB = ca4[1];
            float4 zA = z4[0],  zB = z4[1];
            float cr = ((cA.x*zA.x + cA.y*zA.y) + (cA.z*zA.z + cA.w*zA.w))
                     + ((cB.x*zB.x + cB.y*zB.y) + (cB.z*zB.z + cB.w*zB.w));
            q[j] = s_qT[e * SROW + t] + cr;
            f[j] = s_gi[rc] * svc[j];
        }
        nt_store4(o2 + i, q[0], q[1], q[2], q[3]);
        nt_store4(o0 + i, f[0]+q[0], f[1]+q[1], f[2]+q[2], f[3]+q[3]);
    }
}

// ===========================================================================
// Fallback path (proven R6): aggK + finK, used only if cooperative launch
// is rejected by the runtime.
// ===========================================================================
template <int L, int G>
__global__ __launch_bounds__(256, 8)
void aggK(const float* __restrict__ Se, const float* __restrict__ tt,
          const float* __restrict__ pp, float* __restrict__ agg, int B) {
    constexpr int NSTEP = G * L;
    constexpr int TILES = T_LEN / NSTEP;
    constexpr int RW    = NSTEP + 1;
    constexpr int NT    = 256;
    constexpr int AC_K  = L * 16 + 4;
    constexpr int OV_R  = 0;
    constexpr int OV_P  = G * 72;
    constexpr int O_INV = G * AC_K;
    constexpr int TOTAL = O_INV + RW;

    __shared__ __align__(16) float sm[TOTAL];
    float* s_AC  = sm;
    float* s_R   = sm + OV_R;
    float* s_P   = sm + OV_P;
    float* s_inv = sm + O_INV;

    const int tid  = threadIdx.x;
    const int b    = blockIdx.x / (TILES - 1);
    const int tile = blockIdx.x % (TILES - 1);

    const int base = tile * NSTEP;
    const int off  = (base == 0) ? 0 : 1;
    const int r0   = (base == 0) ? 0 : base - 1;

    const float* ppb = pp + ((size_t)b * T_LEN + r0) * NPP;
    const float* ttb = tt + (size_t)b * T_LEN + r0;

    for (int i = tid; i < RW; i += NT) {
        const float* gp = ppb + i * NPP + 8;
        float gs = 0.f;
        #pragma unroll
        for (int k = 0; k < 9; ++k) gs += gp[k];
        s_inv[i] = __builtin_amdgcn_rcpf(gs);
    }
    __syncthreads();

    for (int i = tid; i < NSTEP * 8; i += NT) {
        int m  = i & 7;
        int ts = i >> 3;
        int rc = ts + off;
        bool first = (base == 0) && (ts == 0);
        int rp = first ? rc : rc - 1;
        float tau_c = ppb[rc * NPP + m];
        float tau_p = ppb[rp * NPP + m];
        float gqh_c = 0.5f * ppb[rc * NPP + 9 + m] * s_inv[rc];
        float gqh_p = 0.5f * ppb[rp * NPP + 9 + m] * s_inv[rp];
        float t_c = ttb[rc];
        float t_p = first ? -ttb[1] : ttb[rp];
        float ee  = __expf((t_p - t_c) * __builtin_amdgcn_rcpf(tau_c + tau_p));
        int kk = ts / L, sl = ts % L;
        s_AC[kk * AC_K + sl * 16 + m]     = ee * ee;
        s_AC[kk * AC_K + sl * 16 + 8 + m] = ee * (gqh_c + gqh_p);
    }
    __syncthreads();

    float Q[8] = {0,0,0,0,0,0,0,0};
    float cumA_c = 1.f;
    if (tid < 72) {
        const int k = tid / 9;
        const int e = tid - k * 9;
        const float* Sg = Se + (size_t)b * T_LEN * 9 + e;
        const int gbase = base + k * L;
        float dS[L];
        {
            float prev = (base == 0 && k == 0) ? 0.f
                                               : Sg[(size_t)(gbase - 1) * 9];
            #pragma unroll
            for (int s = 0; s < L; ++s) {
                float cur = Sg[(size_t)(gbase + s) * 9];
                dS[s] = cur - prev;
                prev = cur;
            }
        }
        const float4* acp = (const float4*)(s_AC + k * AC_K);
        #pragma unroll
        for (int s = 0; s < L; ++s) {
            float4 a0 = acp[4*s], a1 = acp[4*s+1];
            float4 c0v = acp[4*s+2], c1v = acp[4*s+3];
            float d = dS[s];
            Q[0] = a0.x*Q[0] + c0v.x*d;  Q[1] = a0.y*Q[1] + c0v.y*d;
            Q[2] = a0.z*Q[2] + c0v.z*d;  Q[3] = a0.w*Q[3] + c0v.w*d;
            Q[4] = a1.x*Q[4] + c1v.x*d;  Q[5] = a1.y*Q[5] + c1v.y*d;
            Q[6] = a1.z*Q[6] + c1v.z*d;  Q[7] = a1.w*Q[7] + c1v.w*d;
        }
    } else if (tid >= 192) {
        const int u = tid - 192;
        const int k = u >> 3;
        const int m = u & 7;
        #pragma unroll
        for (int s = 0; s < L; ++s)
            cumA_c *= s_AC[k * AC_K + s * 16 + m];
    }
    __syncthreads();

    if (tid < 72) {
        float4* r4 = (float4*)(s_R + 8 * tid);
        r4[0] = make_float4(Q[0], Q[1], Q[2], Q[3]);
        r4[1] = make_float4(Q[4], Q[5], Q[6], Q[7]);
    } else if (tid >= 192) {
        s_P[tid - 192] = cumA_c;
    }
    __syncthreads();

    if (tid < 72) {
        const int e = tid >> 3;
        const int m = tid & 7;
        float z = 0.f, pprod = 1.f;
        #pragma unroll
        for (int k = 0; k < G; ++k) {
            float Pk = s_P[k * 8 + m];
            z = Pk * z + s_R[k * 72 + tid];
            pprod *= Pk;
        }
        float* ap = agg + ((size_t)b * TILES + tile) * 80;
        ap[8 + tid] = z;
        if (e == 0) ap[m] = pprod;
    }
}

template <int L, int G>
__global__ __launch_bounds__(256, 8)
void finK(const float* __restrict__ Se, const float* __restrict__ tt,
          const float* __restrict__ pp, float* __restrict__ out,
          const float* __restrict__ agg, int B) {
    constexpr int NSTEP = G * L;
    constexpr int TILES = T_LEN / NSTEP;
    constexpr int RW    = NSTEP + 1;
    constexpr int NT    = 256;
    constexpr int SROW  = NSTEP + 4;
    constexpr int QT_SZ = 9 * SROW;
    constexpr int CA_K  = L * 8 + 4;
    constexpr int AC_K  = L * 16 + 4;
    constexpr int O_AC  = QT_SZ + G * CA_K;
    constexpr int OV_R  = 0;
    constexpr int OV_P  = G * 72;
    constexpr int OV_Z  = OV_P + G * 8;
    constexpr int O_INV = O_AC + G * AC_K;
    constexpr int O_GI  = O_INV + RW;
    constexpr int O_ZIN = O_GI + RW;
    constexpr int TOTAL = O_ZIN + 72;

    __shared__ __align__(16) float sm[TOTAL];
    float* s_qT  = sm;
    float* s_ca  = sm + QT_SZ;
    float* s_AC  = sm + O_AC;
    float* s_R   = sm + O_AC + OV_R;
    float* s_P   = sm + O_AC + OV_P;
    float* s_Z   = sm + O_AC + OV_Z;
    float* s_inv = sm + O_INV;
    float* s_gi  = sm + O_GI;
    float* s_Zin = sm + O_ZIN;

    const int tid  = threadIdx.x;
    const int b    = blockIdx.x / TILES;
    const int tile = blockIdx.x % TILES;

    const int base = tile * NSTEP;
    const int off  = (base == 0) ? 0 : 1;
    const int r0   = (base == 0) ? 0 : base - 1;

    const float* ppb = pp + ((size_t)b * T_LEN + r0) * NPP;
    const float* ttb = tt + (size_t)b * T_LEN + r0;

    if (tid < 72) {
        float zin = 0.f;
        if (tile > 0) {
            const int m = tid & 7;
            const float* ab = agg + (size_t)b * TILES * 80;
            float Pv[TILES - 1], Rv[TILES - 1];
            #pragma unroll
            for (int j = 0; j < TILES - 1; ++j) {
                if (j < tile) {
                    Pv[j] = ab[j * 80 + m];
                    Rv[j] = ab[j * 80 + 8 + tid];
                }
            }
            #pragma unroll
            for (int j = 0; j < TILES - 1; ++j)
                if (j < tile) zin = Pv[j] * zin + Rv[j];
        }
        s_Zin[tid] = zin;
    } else {
        int i = tid - 72;
        if (i < RW) {
            const float* gp = ppb + i * NPP + 8;
            float gs = 0.f;
            #pragma unroll
            for (int k = 0; k < 9; ++k) gs += gp[k];
            float iv = __builtin_amdgcn_rcpf(gs);
            s_inv[i] = iv;
            s_gi[i]  = gp[0] * iv;
        }
    }
    __syncthreads();

    for (int i = tid; i < NSTEP * 8; i += NT) {
        int m  = i & 7;
        int ts = i >> 3;
        int rc = ts + off;
        bool first = (base == 0) && (ts == 0);
        int rp = first ? rc : rc - 1;
        float tau_c = ppb[rc * NPP + m];
        float tau_p = ppb[rp * NPP + m];
        float gqh_c = 0.5f * ppb[rc * NPP + 9 + m] * s_inv[rc];
        float gqh_p = 0.5f * ppb[rp * NPP + 9 + m] * s_inv[rp];
        float t_c = ttb[rc];
        float t_p = first ? -ttb[1] : ttb[rp];
        float ee  = __expf((t_p - t_c) * __builtin_amdgcn_rcpf(tau_c + tau_p));
        int kk = ts / L, sl = ts % L;
        s_AC[kk * AC_K + sl * 16 + m]     = ee * ee;
        s_AC[kk * AC_K + sl * 16 + 8 + m] = ee * (gqh_c + gqh_p);
    }
    __syncthreads();

    const size_t nOut = (size_t)B * T_LEN * 9;
    float* o0 = out + ((size_t)b * T_LEN + base) * 9;
    float* o1 = o0 + nOut;
    float* o2 = o0 + 2 * nOut;
    const float4* sv4 = (const float4*)(Se + ((size_t)b * T_LEN + base) * 9);

    float Q[8] = {0,0,0,0,0,0,0,0};
    float cumA_c = 1.f;
    if (tid < 72) {
        const int k = tid / 9;
        const int e = tid - k * 9;
        const float* Sg = Se + (size_t)b * T_LEN * 9 + e;
        const int gbase = base + k * L;
        float dS[L];
        {
            float prev = (base == 0 && k == 0) ? 0.f
                                               : Sg[(size_t)(gbase - 1) * 9];
            #pragma unroll
            for (int s = 0; s < L; ++s) {
                float cur = Sg[(size_t)(gbase + s) * 9];
                dS[s] = cur - prev;
                prev = cur;
            }
        }
        const float4* acp = (const float4*)(s_AC + k * AC_K);
        #pragma unroll
        for (int s = 0; s < L; ++s) {
            float4 a0 = acp[4*s], a1 = acp[4*s+1];
            float4 c0v = acp[4*s+2], c1v = acp[4*s+3];
            float d = dS[s];
            Q[0] = a0.x*Q[0] + c0v.x*d;  Q[1] = a0.y*Q[1] + c0v.y*d;
            Q[2] = a0.z*Q[2] + c0v.z*d;  Q[3] = a0.w*Q[3] + c0v.w*d;
            Q[4] = a1.x*Q[4] + c1v.x*d;  Q[5] = a1.y*Q[5] + c1v.y*d;
            Q[6] = a1.z*Q[6] + c1v.z*d;  Q[7] = a1.w*Q[7] + c1v.w*d;
            float qs = ((Q[0]+Q[1])+(Q[2]+Q[3])) + ((Q[4]+Q[5])+(Q[6]+Q[7]));
            s_qT[e * SROW + (k * L + s)] = qs;
        }
    } else if (tid < 192) {
        for (int i4 = tid - 72; i4 < NSTEP * 9 / 4; i4 += 120) {
            float4 sv = sv4[i4];
            int i = i4 * 4;
            nt_store4(o1 + i,
                      s_gi[(i    ) / 9 + off] * sv.x,
                      s_gi[(i + 1) / 9 + off] * sv.y,
                      s_gi[(i + 2) / 9 + off] * sv.z,
                      s_gi[(i + 3) / 9 + off] * sv.w);
        }
    } else {
        const int u = tid - 192;
        const int k = u >> 3;
        const int m = u & 7;
        #pragma unroll
        for (int s = 0; s < L; ++s) {
            cumA_c *= s_AC[k * AC_K + s * 16 + m];
            s_ca[k * CA_K + s * 8 + m] = cumA_c;
        }
    }
    __syncthreads();

    if (tid < 72) {
        float4* r4 = (float4*)(s_R + 8 * tid);
        r4[0] = make_float4(Q[0], Q[1], Q[2], Q[3]);
        r4[1] = make_float4(Q[4], Q[5], Q[6], Q[7]);
    } else if (tid >= 192) {
        s_P[tid - 192] = cumA_c;
    }
    __syncthreads();

    if (tid < 72) {
        const int m = tid & 7;
        float z = s_Zin[tid];
        #pragma unroll
        for (int k = 0; k < G; ++k) {
            s_Z[k * 72 + tid] = z;
            z = s_P[k * 8 + m] * z + s_R[k * 72 + tid];
        }
    }
    __syncthreads();

    for (int i4 = tid; i4 < NSTEP * 9 / 4; i4 += NT) {
        float4 sv = sv4[i4];
        const float svc[4] = {sv.x, sv.y, sv.z, sv.w};
        int i = i4 * 4;
        float q[4], f[4];
        #pragma unroll
        for (int j = 0; j < 4; ++j) {
            int idx = i + j;
            int t = idx / 9, e = idx - t * 9;
            int rc = t + off;
            int k = t >> 4, s = t & 15;
            const float4* ca4 = (const float4*)(s_ca + k * CA_K + s * 8);
            const float4* z4  = (const float4*)(s_Z + k * 72 + e * 8);
            float4 cA = ca4[0], cB = ca4[1];
            float4 zA = z4[0],  zB = z4[1];
            float cr = ((cA.x*zA.x + cA.y*zA.y) + (cA.z*zA.z + cA.w*zA.w))
                     + ((cB.x*zB.x + cB.y*zB.y) + (cB.z*zB.z + cB.w*zB.w));
            q[j] = s_qT[e * SROW + t] + cr;
            f[j] = s_gi[rc] * svc[j];
        }
        nt_store4(o2 + i, q[0], q[1], q[2], q[3]);
        nt_store4(o0 + i, f[0]+q[0], f[1]+q[1], f[2]+q[2], f[3]+q[3]);
    }
}

// ===========================================================================
extern "C" void kernel_launch(void* const* d_in, const int* in_sizes, int n_in,
                              void* d_out, int out_size, void* d_ws, size_t ws_size,
                              hipStream_t stream) {
    const float* Se = (const float*)d_in[0];
    const float* tt = (const float*)d_in[1];
    const float* pp = (const float*)d_in[2];
    float* out = (float*)d_out;

    int B = in_sizes[1] / T_LEN;

    constexpr int L = 16;
    constexpr int G = 8;
    constexpr int NSTEP = G * L;            // 128
    constexpr int TILES = T_LEN / NSTEP;    // 16

    float* agg = (float*)d_ws;              // B*TILES*80 floats

    void* args[6];
    args[0] = (void*)&Se;
    args[1] = (void*)&tt;
    args[2] = (void*)&pp;
    args[3] = (void*)&out;
    args[4] = (void*)&agg;
    args[5] = (void*)&B;

    hipError_t err = hipLaunchCooperativeKernel(
        (const void*)fusedCoop<L, G>,
        dim3(B * TILES), dim3(256), args, 0, stream);

    if (err != hipSuccess) {
        // fallback: proven R6 2-kernel path
        aggK<L, G><<<B * (TILES - 1), dim3(256), 0, stream>>>(
            Se, tt, pp, agg, B);
        finK<L, G><<<B * TILES, dim3(256), 0, stream>>>(
            Se, tt, pp, out, agg, B);
    }
}

// Round 9
// 107.593 us; speedup vs baseline: 3.0491x; 3.0491x over previous
//
#include <hip/hip_runtime.h>

#define T_LEN 2048
#define NMODE 8
#define NPP   17   // 8 tau + 9 g (g[0]=g_infy)

// ===========================================================================
// Round 9: R6 recompute-split skeleton (proven best) + two targeted fixes:
//   1) pp/tt LDS staging restored in BOTH kernels (R0-R3 had it; removal in
//      R4 was bundled+masked). One coalesced 2193-float stage replaces
//      ~6k scattered scalar global loads per block that cannot stay in
//      flight under the 64-VGPR budget.
//   2) Mode-split scan: 2 threads per (k,e) chunk (144 threads), 4 modes
//      each -> per-step dependent-FMA chain halved; qsum combined with one
//      shfl_xor (pairs are lane-adjacent). R-store is an aligned float4 at
//      s_R + 4*tid.
// Protocol conclusions locked: kernel-boundary sync only (R1/R4/R8 all show
// in-kernel grid coordination costs >= 20us on this runtime).
// ===========================================================================
template <int L, int G>
__global__ __launch_bounds__(256, 8)
void aggK(const float* __restrict__ Se,   // [B,T,3,3]
          const float* __restrict__ tt,   // [B,T]
          const float* __restrict__ pp,   // [B,T,17]
          float* __restrict__ agg,        // [B*TILES][80] P[8] then R[72]
          int B) {
    constexpr int NSTEP = G * L;            // 128
    constexpr int TILES = T_LEN / NSTEP;    // 16
    constexpr int RW    = NSTEP + 1;        // 129
    constexpr int NT    = 256;
    constexpr int RAW_SZ = RW * NPP;        // 2193
    constexpr int AC_K  = L * 16 + 4;       // 260
    constexpr int O_T   = RAW_SZ;           // 2193
    constexpr int O_AC  = ((O_T + RW) + 3) & ~3;   // 2324 (16B aligned)
    constexpr int OV_R  = 0;                // G*72 = 576
    constexpr int OV_P  = G * 72;           // G*8  = 64
    static_assert(OV_P + G * 8 <= G * AC_K, "overlay fits");
    constexpr int O_INV = O_AC + G * AC_K;  // 4404
    constexpr int TOTAL = O_INV + RW;       // 4533 floats = 18132 B
    static_assert(TOTAL * 4 <= 20480, "8 blocks/CU");

    __shared__ __align__(16) float sm[TOTAL];
    float* s_raw = sm;
    float* s_t   = sm + O_T;
    float* s_AC  = sm + O_AC;
    float* s_R   = sm + O_AC + OV_R;
    float* s_P   = sm + O_AC + OV_P;
    float* s_inv = sm + O_INV;

    const int tid  = threadIdx.x;
    const int b    = blockIdx.x / (TILES - 1);
    const int tile = blockIdx.x % (TILES - 1);   // 0..14 (tile 15 unused)

    const int base = tile * NSTEP;
    const int off  = (base == 0) ? 0 : 1;
    const int r0   = (base == 0) ? 0 : base - 1;

    // ---- stage pp + t (coalesced) ----
    {
        const float* pr = pp + ((size_t)b * T_LEN + r0) * NPP;
        for (int i = tid; i < RAW_SZ; i += NT) s_raw[i] = pr[i];
        const float* tr = tt + (size_t)b * T_LEN + r0;
        for (int i = tid; i < RW; i += NT) s_t[i] = tr[i];
    }
    __syncthreads();

    // ---- per-row 1/sum(g) ----
    if (tid < RW) {
        float gs = 0.f;
        #pragma unroll
        for (int k = 8; k < NPP; ++k) gs += s_raw[tid * NPP + k];
        s_inv[tid] = __builtin_amdgcn_rcpf(gs);
    }
    __syncthreads();

    // ---- per-(step,mode) coefficients ----
    for (int i = tid; i < NSTEP * 8; i += NT) {
        int m  = i & 7;
        int ts = i >> 3;
        int rc = ts + off;
        bool first = (base == 0) && (ts == 0);
        int rp = first ? rc : rc - 1;
        float tau_c = s_raw[rc * NPP + m];
        float tau_p = s_raw[rp * NPP + m];
        float gqh_c = 0.5f * s_raw[rc * NPP + 9 + m] * s_inv[rc];
        float gqh_p = 0.5f * s_raw[rp * NPP + 9 + m] * s_inv[rp];
        float t_c = s_t[rc];
        float t_p = first ? -s_t[1] : s_t[rp];
        float ee  = __expf((t_p - t_c) * __builtin_amdgcn_rcpf(tau_c + tau_p));
        int kk = ts / L, sl = ts % L;
        s_AC[kk * AC_K + sl * 16 + m]     = ee * ee;              // A
        s_AC[kk * AC_K + sl * 16 + 8 + m] = ee * (gqh_c + gqh_p); // C
    }
    __syncthreads();

    // ---- mode-split chunk scans (tid<144) | cumA products (192..255) ----
    float Q[4] = {0,0,0,0};
    float cumA_c = 1.f;
    if (tid < 144) {
        const int u = tid >> 1;         // (k,e)
        const int h = tid & 1;          // mode half
        const int k = u / 9;
        const int e = u - k * 9;
        const float* Sg = Se + (size_t)b * T_LEN * 9 + e;
        const int gbase = base + k * L;

        float dS[L];
        {
            float prev = (base == 0 && k == 0) ? 0.f
                                               : Sg[(size_t)(gbase - 1) * 9];
            #pragma unroll
            for (int s = 0; s < L; ++s) {
                float cur = Sg[(size_t)(gbase + s) * 9];
                dS[s] = cur - prev;
                prev = cur;
            }
        }

        const float4* acp = (const float4*)(s_AC + k * AC_K);
        #pragma unroll
        for (int s = 0; s < L; ++s) {
            float4 a = acp[4*s + h];
            float4 c = acp[4*s + 2 + h];
            float d = dS[s];
            Q[0] = a.x*Q[0] + c.x*d;  Q[1] = a.y*Q[1] + c.y*d;
            Q[2] = a.z*Q[2] + c.z*d;  Q[3] = a.w*Q[3] + c.w*d;
        }
    } else if (tid >= 192) {
        const int u = tid - 192;
        const int k = u >> 3;
        const int m = u & 7;
        #pragma unroll
        for (int s = 0; s < L; ++s)
            cumA_c *= s_AC[k * AC_K + s * 16 + m];
    }
    __syncthreads();   // last AC reads done -> overlay writable

    if (tid < 144) {
        // offset = 8*(k*9+e) + 4*h = 4*tid (aligned float4)
        *(float4*)(s_R + 4 * tid) = make_float4(Q[0], Q[1], Q[2], Q[3]);
    } else if (tid >= 192) {
        s_P[tid - 192] = cumA_c;
    }
    __syncthreads();

    // ---- compose across chunks; write tile aggregate ----
    if (tid < 72) {
        const int e = tid >> 3;
        const int m = tid & 7;
        float z = 0.f, pprod = 1.f;
        #pragma unroll
        for (int k = 0; k < G; ++k) {
            float Pk = s_P[k * 8 + m];
            z = Pk * z + s_R[k * 72 + tid];
            pprod *= Pk;
        }
        float* ap = agg + ((size_t)b * TILES + tile) * 80;
        ap[8 + tid] = z;
        if (e == 0) ap[m] = pprod;
    }
}

// ===========================================================================
// finK: full per-tile recompute with zin known; writes all three planes.
// ===========================================================================
template <int L, int G>
__global__ __launch_bounds__(256, 8)
void finK(const float* __restrict__ Se,   // [B,T,3,3]
          const float* __restrict__ tt,   // [B,T]
          const float* __restrict__ pp,   // [B,T,17]
          float* __restrict__ out,        // [3,B,T,3,3]
          const float* __restrict__ agg,  // [B*TILES][80]
          int B) {
    constexpr int NSTEP = G * L;            // 128
    constexpr int TILES = T_LEN / NSTEP;    // 16
    constexpr int RW    = NSTEP + 1;        // 129
    constexpr int NT    = 256;
    constexpr int SROW  = NSTEP + 4;        // 132
    constexpr int QT_SZ = 9 * SROW;         // 1188
    constexpr int CA_K  = L * 8 + 4;        // 132
    constexpr int AC_K  = L * 16 + 4;       // 260
    constexpr int RAW_SZ = RW * NPP;        // 2193
    constexpr int UNION_SZ = (RAW_SZ > QT_SZ + G * CA_K) ? RAW_SZ
                                                         : (QT_SZ + G * CA_K);
    constexpr int O_AC  = UNION_SZ;         // 2244 (16B aligned: 2244%4==0)
    constexpr int OV_R  = 0;                     // G*72 = 576
    constexpr int OV_P  = G * 72;                // G*8  = 64
    constexpr int OV_Z  = OV_P + G * 8;          // G*72 = 576
    static_assert(OV_Z + G * 72 <= G * AC_K, "overlay fits");
    constexpr int O_T   = O_AC + G * AC_K;       // 4324
    constexpr int O_INV = O_T + RW;              // 4453
    constexpr int O_GI  = O_INV + RW;            // 4582
    constexpr int O_ZIN = O_GI + RW;             // 4711
    constexpr int TOTAL = O_ZIN + 72;            // 4783 floats = 19132 B
    static_assert(TOTAL * 4 <= 20480, "8 blocks/CU");
    static_assert(L == 16, "epilogue uses t>>4 / t&15");

    __shared__ __align__(16) float sm[TOTAL];
    float* s_raw = sm;                       // union: staged inputs
    float* s_qT  = sm;                       // union: qsum transposed [e][t]
    float* s_ca  = sm + QT_SZ;               // union: cumA skewed [k][s][8]
    float* s_AC  = sm + O_AC;                // coeffs (dead after scan)
    float* s_R   = sm + O_AC + OV_R;
    float* s_P   = sm + O_AC + OV_P;
    float* s_Z   = sm + O_AC + OV_Z;
    float* s_t   = sm + O_T;
    float* s_inv = sm + O_INV;
    float* s_gi  = sm + O_GI;
    float* s_Zin = sm + O_ZIN;

    const int tid  = threadIdx.x;
    const int b    = blockIdx.x / TILES;
    const int tile = blockIdx.x % TILES;

    const int base = tile * NSTEP;
    const int off  = (base == 0) ? 0 : 1;
    const int r0   = (base == 0) ? 0 : base - 1;

    // ---- phase 0: zin batch loads (tid<72, issued first, latency hidden
    //      under the staging loop) + stage pp/t (all threads) ----
    float Pv[TILES - 1], Rv[TILES - 1];
    if (tid < 72 && tile > 0) {
        const int m = tid & 7;
        const float* ab = agg + (size_t)b * TILES * 80;
        #pragma unroll
        for (int j = 0; j < TILES - 1; ++j) {
            if (j < tile) {
                Pv[j] = ab[j * 80 + m];
                Rv[j] = ab[j * 80 + 8 + tid];
            }
        }
    }
    {
        const float* pr = pp + ((size_t)b * T_LEN + r0) * NPP;
        for (int i = tid; i < RAW_SZ; i += NT) s_raw[i] = pr[i];
        const float* tr = tt + (size_t)b * T_LEN + r0;
        for (int i = tid; i < RW; i += NT) s_t[i] = tr[i];
    }
    if (tid < 72) {
        float zin = 0.f;
        if (tile > 0) {
            #pragma unroll
            for (int j = 0; j < TILES - 1; ++j)
                if (j < tile) zin = Pv[j] * zin + Rv[j];
        }
        s_Zin[tid] = zin;
    }
    __syncthreads();

    // ---- per-row 1/sum(g), g_infy/sum ----
    if (tid < RW) {
        float gs = 0.f;
        #pragma unroll
        for (int k = 8; k < NPP; ++k) gs += s_raw[tid * NPP + k];
        float iv = __builtin_amdgcn_rcpf(gs);
        s_inv[tid] = iv;
        s_gi[tid]  = s_raw[tid * NPP + 8] * iv;
    }
    __syncthreads();

    // ---- coefficients ----
    for (int i = tid; i < NSTEP * 8; i += NT) {
        int m  = i & 7;
        int ts = i >> 3;
        int rc = ts + off;
        bool first = (base == 0) && (ts == 0);
        int rp = first ? rc : rc - 1;
        float tau_c = s_raw[rc * NPP + m];
        float tau_p = s_raw[rp * NPP + m];
        float gqh_c = 0.5f * s_raw[rc * NPP + 9 + m] * s_inv[rc];
        float gqh_p = 0.5f * s_raw[rp * NPP + 9 + m] * s_inv[rp];
        float t_c = s_t[rc];
        float t_p = first ? -s_t[1] : s_t[rp];
        float ee  = __expf((t_p - t_c) * __builtin_amdgcn_rcpf(tau_c + tau_p));
        int kk = ts / L, sl = ts % L;
        s_AC[kk * AC_K + sl * 16 + m]     = ee * ee;              // A
        s_AC[kk * AC_K + sl * 16 + 8 + m] = ee * (gqh_c + gqh_p); // C
    }
    __syncthreads();   // s_raw consumed; union becomes qT/ca

    const size_t nOut = (size_t)B * T_LEN * 9;
    float* o0 = out + ((size_t)b * T_LEN + base) * 9;
    float* o1 = o0 + nOut;
    float* o2 = o0 + 2 * nOut;
    const float4* sv4 = (const float4*)(Se + ((size_t)b * T_LEN + base) * 9);

    // ---- scan: mode-split scans (tid<144) | S_infy (144..191)
    //      | cumA (192..255) ----
    float Q[4] = {0,0,0,0};
    float cumA_c = 1.f;
    if (tid < 144) {
        const int u = tid >> 1;
        const int h = tid & 1;
        const int k = u / 9;
        const int e = u - k * 9;
        const float* Sg = Se + (size_t)b * T_LEN * 9 + e;
        const int gbase = base + k * L;

        float dS[L];
        {
            float prev = (base == 0 && k == 0) ? 0.f
                                               : Sg[(size_t)(gbase - 1) * 9];
            #pragma unroll
            for (int s = 0; s < L; ++s) {
                float cur = Sg[(size_t)(gbase + s) * 9];
                dS[s] = cur - prev;
                prev = cur;
            }
        }

        const float4* acp = (const float4*)(s_AC + k * AC_K);
        #pragma unroll
        for (int s = 0; s < L; ++s) {
            float4 a = acp[4*s + h];
            float4 c = acp[4*s + 2 + h];
            float d = dS[s];
            Q[0] = a.x*Q[0] + c.x*d;  Q[1] = a.y*Q[1] + c.y*d;
            Q[2] = a.z*Q[2] + c.z*d;  Q[3] = a.w*Q[3] + c.w*d;
            float qh = (Q[0] + Q[1]) + (Q[2] + Q[3]);
            float qs = qh + __shfl_xor(qh, 1);
            if (h == 0) s_qT[e * SROW + (k * L + s)] = qs;
        }
    } else if (tid < 192) {
        // S_infy plane — hidden behind the chunk scans
        for (int i4 = tid - 144; i4 < NSTEP * 9 / 4; i4 += 48) {
            float4 sv = sv4[i4];
            int i = i4 * 4;
            float f0 = s_gi[(i    ) / 9 + off] * sv.x;
            float f1 = s_gi[(i + 1) / 9 + off] * sv.y;
            float f2 = s_gi[(i + 2) / 9 + off] * sv.z;
            float f3 = s_gi[(i + 3) / 9 + off] * sv.w;
            ((float4*)o1)[i4] = make_float4(f0, f1, f2, f3);
        }
    } else {
        const int u = tid - 192;
        const int k = u >> 3;
        const int m = u & 7;
        #pragma unroll
        for (int s = 0; s < L; ++s) {
            cumA_c *= s_AC[k * AC_K + s * 16 + m];
            s_ca[k * CA_K + s * 8 + m] = cumA_c;
        }
    }
    __syncthreads();   // last AC reads done -> overlay writable

    if (tid < 144) {
        *(float4*)(s_R + 4 * tid) = make_float4(Q[0], Q[1], Q[2], Q[3]);
    } else if (tid >= 192) {
        s_P[tid - 192] = cumA_c;
    }
    __syncthreads();

    // ---- compose seeded with zin: entering state per chunk ----
    if (tid < 72) {
        const int m = tid & 7;
        float z = s_Zin[tid];
        #pragma unroll
        for (int k = 0; k < G; ++k) {
            s_Z[k * 72 + tid] = z;
            z = s_P[k * 8 + m] * z + s_R[k * 72 + tid];
        }
    }
    __syncthreads();

    // ---- epilogue: final S and Q_sum planes ----
    for (int i4 = tid; i4 < NSTEP * 9 / 4; i4 += NT) {
        float4 sv = sv4[i4];   // cache-warm re-read
        const float svc[4] = {sv.x, sv.y, sv.z, sv.w};
        int i = i4 * 4;
        float q[4], f[4];
        #pragma unroll
        for (int j = 0; j < 4; ++j) {
            int idx = i + j;
            int t = idx / 9, e = idx - t * 9;
            int rc = t + off;
            int k = t >> 4, s = t & 15;
            const float4* ca4 = (const float4*)(s_ca + k * CA_K + s * 8);
            const float4* z4  = (const float4*)(s_Z + k * 72 + e * 8);
            float4 cA = ca4[0], cB = ca4[1];
            float4 zA = z4[0],  zB = z4[1];
            float cr = ((cA.x*zA.x + cA.y*zA.y) + (cA.z*zA.z + cA.w*zA.w))
                     + ((cB.x*zB.x + cB.y*zB.y) + (cB.z*zB.z + cB.w*zB.w));
            q[j] = s_qT[e * SROW + t] + cr;
            f[j] = s_gi[rc] * svc[j];
        }
        ((float4*)o2)[i4] = make_float4(q[0], q[1], q[2], q[3]);
        ((float4*)o0)[i4] = make_float4(f[0]+q[0], f[1]+q[1],
                                        f[2]+q[2], f[3]+q[3]);
    }
}

// ===========================================================================
extern "C" void kernel_launch(void* const* d_in, const int* in_sizes, int n_in,
                              void* d_out, int out_size, void* d_ws, size_t ws_size,
                              hipStream_t stream) {
    const float* Se = (const float*)d_in[0];
    const float* tt = (const float*)d_in[1];
    const float* pp = (const float*)d_in[2];
    float* out = (float*)d_out;

    int B = in_sizes[1] / T_LEN;

    constexpr int L = 16;
    constexpr int G = 8;
    constexpr int NSTEP = G * L;            // 128
    constexpr int TILES = T_LEN / NSTEP;    // 16

    float* agg = (float*)d_ws;              // B*TILES*80 floats

    aggK<L, G><<<B * (TILES - 1), dim3(256), 0, stream>>>(
        Se, tt, pp, agg, B);
    finK<L, G><<<B * TILES, dim3(256), 0, stream>>>(
        Se, tt, pp, out, agg, B);
}

// Round 10
// 99.056 us; speedup vs baseline: 3.3119x; 1.0862x over previous
//
#include <hip/hip_runtime.h>

#define T_LEN 2048
#define NMODE 8
#define NPP   17   // 8 tau + 9 g (g[0]=g_infy)

// ===========================================================================
// Round 10 = exact revert to Round 5 (measured best: 98.4us, vs 108.4
// session baseline). R9's mode-split scan regressed (-9us: __shfl_xor
// inside the 16-step serial loop = 16 dependent ds_bpermute latencies);
// R6/R7 alternatives were neutral. Plateau evidence (R5-R9): kernel time
// ~26us is latency-chain-bound (VALUBusy 16%, HBM 12%, no pipe saturated);
// harness floor ~72us dominates dur_us.
//
// Structure: waitless 2-kernel pipeline.
//   scanK (grid B*TILES): per 128-step tile: coeff pass -> chunk scans ->
//     in-block compose; writes S_infy plane, tile-locally-corrected q
//     plane, tile-folded cumA caT[t,m] = Pp[k,m]*ca[k][s,m], and per-tile
//     aggregates (P[8], R[72]).
//   finishK (grid B*TILES): batched one-latency load of <=15 predecessor
//     aggregates, 15-FMA spine fold in registers, then stream
//     corr = caT[t] . Ztile_in[e] into final S / Q_sum planes.
// No atomics, no flags, no memset, no in-kernel grid sync (R1/R4/R8 show
// any in-kernel grid coordination costs >=10us on this runtime).
// Both kernels 8 blocks/CU (LDS <= 18.3KB, VGPR <= 64).
// ===========================================================================
template <int L, int G>
__global__ __launch_bounds__(256, 8)
void scanK(const float* __restrict__ Se,   // [B,T,3,3]
           const float* __restrict__ tt,   // [B,T]
           const float* __restrict__ pp,   // [B,T,17]
           float* __restrict__ out,        // [3,B,T,3,3]
           float* __restrict__ caT,        // [B,T,8] tile-folded cumA
           float* __restrict__ agg,        // [B*TILES][80] P[8] then R[72]
           int B) {
    constexpr int NSTEP = G * L;            // 128
    constexpr int TILES = T_LEN / NSTEP;    // 16
    constexpr int RW    = NSTEP + 1;        // 129
    constexpr int NT    = 256;
    constexpr int SROW  = NSTEP + 4;        // 132
    constexpr int QT_SZ = 9 * SROW;         // 1188
    constexpr int CA_K  = L * 8 + 4;        // 132
    constexpr int AC_K  = L * 16 + 4;       // 260
    constexpr int O_AC  = QT_SZ + G * CA_K; // 2244
    // overlay inside AC region (AC dead after scan phase):
    constexpr int OV_ZREL = 0;                   // G*72 = 576
    constexpr int OV_PP   = G * 72;              // G*8  = 64
    constexpr int OV_R    = OV_PP + G * 8;       // G*72 = 576
    constexpr int OV_P    = OV_R + G * 72;       // G*8  = 64
    static_assert(OV_P + G * 8 <= G * AC_K, "overlay fits in AC region");
    constexpr int O_INV = O_AC + G * AC_K;       // 4324
    constexpr int O_GI  = O_INV + RW;            // 4453
    constexpr int TOTAL = O_GI + RW;             // 4582 floats = 18328 B
    static_assert(TOTAL * 4 <= 20480, "LDS must allow 8 blocks/CU");
    static_assert(L == 16, "epilogue uses t>>4 / t&15");

    __shared__ __align__(16) float sm[TOTAL];
    float* s_qT   = sm;                      // qsum transposed [e][t]
    float* s_ca   = sm + QT_SZ;              // cumA skewed [k][s][8]
    float* s_AC   = sm + O_AC;               // coeffs (dead after scan)
    float* s_Zrel = sm + O_AC + OV_ZREL;
    float* s_Pp   = sm + O_AC + OV_PP;
    float* s_R    = sm + O_AC + OV_R;
    float* s_P    = sm + O_AC + OV_P;
    float* s_inv  = sm + O_INV;
    float* s_gi   = sm + O_GI;

    const int tid = threadIdx.x;
    const int b    = blockIdx.x / TILES;
    const int tile = blockIdx.x % TILES;

    const int base = tile * NSTEP;
    const int off  = (base == 0) ? 0 : 1;
    const int r0   = (base == 0) ? 0 : base - 1;

    const float* ppb = pp + ((size_t)b * T_LEN + r0) * NPP;
    const float* ttb = tt + (size_t)b * T_LEN + r0;

    // ---- per-row 1/sum(g), g_infy/sum (global reads) ----
    for (int i = tid; i < RW; i += NT) {
        const float* gp = ppb + i * NPP + 8;
        float gs = 0.f;
        #pragma unroll
        for (int k = 0; k < 9; ++k) gs += gp[k];
        float iv = __builtin_amdgcn_rcpf(gs);
        s_inv[i] = iv;
        s_gi[i]  = gp[0] * iv;
    }
    __syncthreads();

    // ---- per-(step,mode) coefficients (global reads, L1/L2-warm) ----
    for (int i = tid; i < NSTEP * 8; i += NT) {
        int m  = i & 7;
        int ts = i >> 3;
        int rc = ts + off;
        bool first = (base == 0) && (ts == 0);
        int rp = first ? rc : rc - 1;
        float tau_c = ppb[rc * NPP + m];
        float tau_p = ppb[rp * NPP + m];
        float gqh_c = 0.5f * ppb[rc * NPP + 9 + m] * s_inv[rc];
        float gqh_p = 0.5f * ppb[rp * NPP + 9 + m] * s_inv[rp];
        float t_c = ttb[rc];
        float t_p = first ? -ttb[1] : ttb[rp];
        float ee  = __expf((t_p - t_c) * __builtin_amdgcn_rcpf(tau_c + tau_p));
        int kk = ts / L, sl = ts % L;
        s_AC[kk * AC_K + sl * 16 + m]     = ee * ee;              // A
        s_AC[kk * AC_K + sl * 16 + 8 + m] = ee * (gqh_c + gqh_p); // C
    }
    __syncthreads();

    const size_t nOut = (size_t)B * T_LEN * 9;
    float* o1 = out + nOut + ((size_t)b * T_LEN + base) * 9;
    float* o2 = out + 2 * nOut + ((size_t)b * T_LEN + base) * 9;
    const float4* sv4 = (const float4*)(Se + ((size_t)b * T_LEN + base) * 9);

    // ---- scan phase: chunk scans (tid<72) | S_infy plane (72..191)
    //                  | cumA (192..255) ----
    float Q[8] = {0,0,0,0,0,0,0,0};
    float cumA_c = 1.f;
    if (tid < 72) {
        const int k = tid / 9;
        const int e = tid - k * 9;
        const float* Sg = Se + (size_t)b * T_LEN * 9 + e;
        const int gbase = base + k * L;

        float dS[L];
        {
            float prev = (base == 0 && k == 0) ? 0.f
                                               : Sg[(size_t)(gbase - 1) * 9];
            #pragma unroll
            for (int s = 0; s < L; ++s) {
                float cur = Sg[(size_t)(gbase + s) * 9];
                dS[s] = cur - prev;
                prev = cur;
            }
        }

        const float4* acp = (const float4*)(s_AC + k * AC_K);
        #pragma unroll
        for (int s = 0; s < L; ++s) {
            float4 a0 = acp[4*s], a1 = acp[4*s+1];
            float4 c0v = acp[4*s+2], c1v = acp[4*s+3];
            float d = dS[s];
            Q[0] = a0.x*Q[0] + c0v.x*d;  Q[1] = a0.y*Q[1] + c0v.y*d;
            Q[2] = a0.z*Q[2] + c0v.z*d;  Q[3] = a0.w*Q[3] + c0v.w*d;
            Q[4] = a1.x*Q[4] + c1v.x*d;  Q[5] = a1.y*Q[5] + c1v.y*d;
            Q[6] = a1.z*Q[6] + c1v.z*d;  Q[7] = a1.w*Q[7] + c1v.w*d;
            float qs = ((Q[0]+Q[1])+(Q[2]+Q[3])) + ((Q[4]+Q[5])+(Q[6]+Q[7]));
            s_qT[e * SROW + (k * L + s)] = qs;
        }
    } else if (tid < 192) {
        // S_infy plane — hidden behind the chunk scans
        for (int i4 = tid - 72; i4 < NSTEP * 9 / 4; i4 += 120) {
            float4 sv = sv4[i4];
            int i = i4 * 4;
            float f0 = s_gi[(i    ) / 9 + off] * sv.x;
            float f1 = s_gi[(i + 1) / 9 + off] * sv.y;
            float f2 = s_gi[(i + 2) / 9 + off] * sv.z;
            float f3 = s_gi[(i + 3) / 9 + off] * sv.w;
            ((float4*)o1)[i4] = make_float4(f0, f1, f2, f3);
        }
    } else {
        const int u = tid - 192;
        const int k = u >> 3;
        const int m = u & 7;
        #pragma unroll
        for (int s = 0; s < L; ++s) {
            cumA_c *= s_AC[k * AC_K + s * 16 + m];
            s_ca[k * CA_K + s * 8 + m] = cumA_c;
        }
    }
    __syncthreads();   // last AC reads done -> overlay region now writable

    if (tid < 72) {
        float4* r4 = (float4*)(s_R + 8 * tid);   // k*72 + e*8 == 8*tid
        r4[0] = make_float4(Q[0], Q[1], Q[2], Q[3]);
        r4[1] = make_float4(Q[4], Q[5], Q[6], Q[7]);
    } else if (tid >= 192) {
        s_P[tid - 192] = cumA_c;
    }
    __syncthreads();

    // ---- compose across chunks (72 threads = (e,m)); write aggregates ----
    if (tid < 72) {
        const int e = tid >> 3;
        const int m = tid & 7;
        float z = 0.f, pprod = 1.f;
        #pragma unroll
        for (int k = 0; k < G; ++k) {
            s_Zrel[k * 72 + tid] = z;
            if (e == 0) s_Pp[k * 8 + m] = pprod;
            float Pk = s_P[k * 8 + m];
            z = Pk * z + s_R[k * 72 + tid];
            pprod *= Pk;
        }
        if (tile != TILES - 1) {   // last tile has no consumers
            float* ap = agg + ((size_t)b * TILES + tile) * 80;
            ap[8 + tid] = z;
            if (e == 0) ap[m] = pprod;
        }
    }
    __syncthreads();

    // ---- tile-folded cumA: caT[t,m] = Pp[k,m] * ca[k][s,m] ----
    {
        int k = tid >> 5;           // 0..7
        int s = (tid >> 1) & 15;    // 0..15
        int h = tid & 1;            // 0..1
        float4 cv = *(const float4*)(s_ca + k * CA_K + s * 8 + h * 4);
        float4 pv = *(const float4*)(s_Pp + k * 8 + h * 4);
        float4 ov = make_float4(cv.x*pv.x, cv.y*pv.y, cv.z*pv.z, cv.w*pv.w);
        *(float4*)(caT + (((size_t)b * T_LEN + base) + k * L + s) * 8 + h * 4)
            = ov;
    }

    // ---- epilogue: q plane with IN-TILE correction folded (zin = 0) ----
    for (int i4 = tid; i4 < NSTEP * 9 / 4; i4 += NT) {
        int i = i4 * 4;
        float q[4];
        #pragma unroll
        for (int j = 0; j < 4; ++j) {
            int idx = i + j;
            int t = idx / 9, e = idx - t * 9;
            int k = t >> 4, s = t & 15;
            const float4* ca4 = (const float4*)(s_ca + k * CA_K + s * 8);
            const float4* z4  = (const float4*)(s_Zrel + k * 72 + e * 8);
            float4 cA = ca4[0], cB = ca4[1];
            float4 zA = z4[0],  zB = z4[1];
            float cr = ((cA.x*zA.x + cA.y*zA.y) + (cA.z*zA.z + cA.w*zA.w))
                     + ((cB.x*zB.x + cB.y*zB.y) + (cB.z*zB.z + cB.w*zB.w));
            q[j] = s_qT[e * SROW + t] + cr;
        }
        ((float4*)o2)[i4] = make_float4(q[0], q[1], q[2], q[3]);
    }
}

// ===========================================================================
// finishK: spine fold (old phaseB, now 15 in-register FMAs) + correction
// stream (old phaseC). One block per tile.
// ===========================================================================
template <int L, int G>
__global__ __launch_bounds__(256, 8)
void finishK(float* __restrict__ out,
             const float* __restrict__ caT,   // [B,T,8]
             const float* __restrict__ agg,   // [B*TILES][80]
             int B) {
    constexpr int NSTEP = G * L;            // 128
    constexpr int TILES = T_LEN / NSTEP;    // 16
    constexpr int NT    = 256;

    __shared__ __align__(16) float s_Z[80];
    __shared__ __align__(16) float s_ca[NSTEP * 8];

    const int tid  = threadIdx.x;
    const int b    = blockIdx.x / TILES;
    const int tile = blockIdx.x % TILES;
    const int base = tile * NSTEP;

    // stage tile-folded cumA (coalesced float4)
    {
        const float4* c4 = (const float4*)(caT + ((size_t)b * T_LEN + base) * 8);
        for (int i = tid; i < NSTEP * 8 / 4; i += NT)
            ((float4*)s_ca)[i] = c4[i];
    }

    // spine fold: batched predicated loads (one latency), 15 serial FMAs
    if (tid < 72) {
        const int m = tid & 7;
        float zin = 0.f;
        if (tile > 0) {
            const float* ab = agg + (size_t)b * TILES * 80;
            float Pv[TILES - 1], Rv[TILES - 1];
            #pragma unroll
            for (int j = 0; j < TILES - 1; ++j) {
                if (j < tile) {
                    Pv[j] = ab[j * 80 + m];
                    Rv[j] = ab[j * 80 + 8 + tid];
                }
            }
            #pragma unroll
            for (int j = 0; j < TILES - 1; ++j)
                if (j < tile) zin = Pv[j] * zin + Rv[j];
        }
        s_Z[tid] = zin;
    }
    __syncthreads();

    // correction stream: S = S_infy + (q_local + corr); Q_sum = q_local + corr
    const size_t nOut = (size_t)B * T_LEN * 9;
    float* o0 = out + ((size_t)b * T_LEN + base) * 9;
    const float4* sf4 = (const float4*)(o0 + nOut);
    float4* s4 = (float4*)o0;
    float4* q4 = (float4*)(o0 + 2 * nOut);

    for (int i4 = tid; i4 < NSTEP * 9 / 4; i4 += NT) {
        float4 qv = q4[i4];
        float4 fv = sf4[i4];
        int i = i4 * 4;
        float corr[4];
        #pragma unroll
        for (int j = 0; j < 4; ++j) {
            int idx = i + j;
            int t = idx / 9, e = idx - t * 9;
            const float4* ca4 = (const float4*)(s_ca + t * 8);
            const float4* z4  = (const float4*)(s_Z + e * 8);
            float4 cA = ca4[0], cB = ca4[1];
            float4 zA = z4[0],  zB = z4[1];
            corr[j] = ((cA.x*zA.x + cA.y*zA.y) + (cA.z*zA.z + cA.w*zA.w))
                    + ((cB.x*zB.x + cB.y*zB.y) + (cB.z*zB.z + cB.w*zB.w));
        }
        float4 qn = make_float4(qv.x + corr[0], qv.y + corr[1],
                                qv.z + corr[2], qv.w + corr[3]);
        q4[i4] = qn;
        s4[i4] = make_float4(fv.x + qn.x, fv.y + qn.y,
                             fv.z + qn.z, fv.w + qn.w);
    }
}

// ===========================================================================
extern "C" void kernel_launch(void* const* d_in, const int* in_sizes, int n_in,
                              void* d_out, int out_size, void* d_ws, size_t ws_size,
                              hipStream_t stream) {
    const float* Se = (const float*)d_in[0];
    const float* tt = (const float*)d_in[1];
    const float* pp = (const float*)d_in[2];
    float* out = (float*)d_out;

    int B = in_sizes[1] / T_LEN;

    constexpr int L = 16;
    constexpr int G = 8;
    constexpr int NSTEP = G * L;            // 128
    constexpr int TILES = T_LEN / NSTEP;    // 16

    float* caT = (float*)d_ws;                              // B*T*8 floats
    float* agg = caT + (size_t)B * T_LEN * 8;               // B*TILES*80

    scanK<L, G><<<B * TILES, dim3(256), 0, stream>>>(
        Se, tt, pp, out, caT, agg, B);
    finishK<L, G><<<B * TILES, dim3(256), 0, stream>>>(
        out, caT, agg, B);
}